// Round 4
// baseline (703.750 us; speedup 1.0000x reference)
//
#include <hip/hip_runtime.h>

// Problem constants
#define BATCH 32
#define TT    2048
#define HH    1024
#define MTOT  (BATCH * TT)   // 65536

typedef unsigned short ushort_t;
typedef short sh8 __attribute__((ext_vector_type(8)));
typedef float f4 __attribute__((ext_vector_type(4)));
typedef unsigned short us8 __attribute__((ext_vector_type(8)));

__device__ __forceinline__ ushort_t f2bf(float f) {
    unsigned u = __float_as_uint(f);
    u = (u + 0x7fffu + ((u >> 16) & 1u)) >> 16;
    return (ushort_t)u;
}
__device__ __forceinline__ float bf2f(ushort_t h) {
    return __uint_as_float(((unsigned)h) << 16);
}
__device__ __forceinline__ float fast_tanh(float x) {
    float e = __expf(2.0f * x);
    return 1.0f - 2.0f * __builtin_amdgcn_rcpf(e + 1.0f);
}

__device__ __forceinline__ void glds16(const void* g, void* l) {
    __builtin_amdgcn_global_load_lds(
        (const __attribute__((address_space(1))) void*)g,
        (__attribute__((address_space(3))) void*)l, 16, 0, 0);
}

// ---------------- fp32 -> bf16 convert (8 elems/thread) ----------------
__global__ void cvt_bf16_k(const float* __restrict__ in, ushort_t* __restrict__ out, long n) {
    long i = ((long)blockIdx.x * blockDim.x + threadIdx.x) * 8;
    if (i + 8 > n) return;
    float4 a = *(const float4*)(in + i);
    float4 b = *(const float4*)(in + i + 4);
    us8 o;
    o[0]=f2bf(a.x); o[1]=f2bf(a.y); o[2]=f2bf(a.z); o[3]=f2bf(a.w);
    o[4]=f2bf(b.x); o[5]=f2bf(b.y); o[6]=f2bf(b.z); o[7]=f2bf(b.w);
    *(us8*)(out + i) = o;
}

// ---------------- q_proj = query @ Wq.T + bq + bv ----------------
__global__ void qproj_k(const float* __restrict__ query, const float* __restrict__ Wq,
                        const float* __restrict__ bq, const float* __restrict__ bv,
                        float* __restrict__ qp) {
    int o = blockIdx.x, tid = threadIdx.x;
    float4 w4 = *(const float4*)(Wq + (long)o * HH + tid * 4);
    __shared__ float sm[BATCH][4];
    int wid = tid >> 6, lane = tid & 63;
    for (int b = 0; b < BATCH; ++b) {
        float4 q4 = *(const float4*)(query + (long)b * HH + tid * 4);
        float p = q4.x*w4.x + q4.y*w4.y + q4.z*w4.z + q4.w*w4.w;
        #pragma unroll
        for (int m = 1; m < 64; m <<= 1) p += __shfl_xor(p, m);
        if (lane == 0) sm[b][wid] = p;
    }
    __syncthreads();
    if (tid < BATCH) {
        float s = sm[tid][0] + sm[tid][1] + sm[tid][2] + sm[tid][3] + bq[o] + bv[o];
        qp[(long)tid * HH + o] = s;
    }
}

// ---------------- fused score GEMM, restructured K-loop ----------------
// A (values bf16) staged via double-buffered global_load_lds.
// B (Wv bf16, 2 MB, L2-resident) loaded straight to registers, prefetched 1 iter ahead.
// One __syncthreads per K-iter; its vmcnt(0) drains loads issued a full MFMA phase earlier.
#define BM 128
#define BN 128
#define BK 64

__global__ __launch_bounds__(256, 2) void score_gemm_k(
    const ushort_t* __restrict__ A, const ushort_t* __restrict__ Bw,
    const float* __restrict__ qp, const float* __restrict__ Vw,
    float* __restrict__ score)
{
    __shared__ ushort_t As[2][BM * BK];   // 2 x 16 KB, double-buffered
    int tid = threadIdx.x;

    // XCD-aware swizzle: the 8 n-tiles of one m-tile share bx%8 -> same XCD (A reuse in L2)
    int bx = blockIdx.x;
    int x  = bx & 7;
    int s  = bx >> 3;
    int nt = s & 7;
    int mt = ((s >> 3) << 3) | x;          // 0..511
    const long m0 = (long)mt * BM;
    const int  n0 = nt * BN;

    int wid  = tid >> 6, lane = tid & 63;
    int quad = lane >> 4, l16 = lane & 15;
    int wrow = (wid >> 1) * 64, wcol = (wid & 1) * 64;

    f4 acc[4][4] = {};

    // A staging: 4 glds rounds; round c: row = c*32 + tid>>3, seg = tid&7, XOR key = row&7
    int srow = tid >> 3;           // 0..31
    int sseg = tid & 7;
    int xseg = sseg ^ (srow & 7);
    const ushort_t* Ag = A + (m0 + srow) * (long)HH + xseg * 8;
    char* AsB0 = (char*)&As[0][0];
    char* AsB1 = (char*)&As[1][0];
    const int woff = wid * 1024;   // wave-uniform base; HW adds lane*16

    // B direct-load bases: row n = n0 + wcol + j*16 + l16, k-offset = quad*8
    const ushort_t* Bg[4];
    #pragma unroll
    for (int j = 0; j < 4; ++j)
        Bg[j] = Bw + (long)(n0 + wcol + j * 16 + l16) * HH + quad * 8;

    us8 bcur[4][2], bnext[4][2];

    // ---- prologue: stage A(0), load B(0) ----
    #pragma unroll
    for (int c = 0; c < 4; ++c)
        glds16(Ag + (long)c * 32 * HH, AsB0 + c * 4096 + woff);
    #pragma unroll
    for (int j = 0; j < 4; ++j)
        #pragma unroll
        for (int kq = 0; kq < 2; ++kq)
            bcur[j][kq] = *(const us8*)(Bg[j] + kq * 32);
    __syncthreads();

    for (int kt = 0; kt < HH / BK; ++kt) {
        const int kb = kt * BK;
        char* cb = (kt & 1) ? AsB1 : AsB0;
        char* nb = (kt & 1) ? AsB0 : AsB1;

        // prefetch A(kt+1) into the other LDS buffer (safe: barrier at end of kt-1
        // guarantees everyone finished ds_reading that buffer)
        if (kt + 1 < HH / BK) {
            #pragma unroll
            for (int c = 0; c < 4; ++c)
                glds16(Ag + (long)c * 32 * HH + kb + BK, nb + c * 4096 + woff);
        }

        // LDS -> A fragments (XOR-swizzled, conflict-free)
        sh8 af[4][2];
        #pragma unroll
        for (int i = 0; i < 4; ++i) {
            int r = wrow + i * 16 + l16;
            const char* base = cb + r * 128;
            #pragma unroll
            for (int kq = 0; kq < 2; ++kq) {
                int sg = (kq * 4 + quad) ^ (r & 7);
                af[i][kq] = *(const sh8*)(base + sg * 16);
            }
        }

        // prefetch B(kt+1) global -> regs (L2-resident; full MFMA phase to cover latency)
        if (kt + 1 < HH / BK) {
            #pragma unroll
            for (int j = 0; j < 4; ++j)
                #pragma unroll
                for (int kq = 0; kq < 2; ++kq)
                    bnext[j][kq] = *(const us8*)(Bg[j] + kb + BK + kq * 32);
        }

        #pragma unroll
        for (int kq = 0; kq < 2; ++kq)
            #pragma unroll
            for (int i = 0; i < 4; ++i)
                #pragma unroll
                for (int j = 0; j < 4; ++j)
                    acc[i][j] = __builtin_amdgcn_mfma_f32_16x16x32_bf16(
                        af[i][kq], *(sh8*)&bcur[j][kq], acc[i][j], 0, 0, 0);

        #pragma unroll
        for (int j = 0; j < 4; ++j)
            #pragma unroll
            for (int kq = 0; kq < 2; ++kq)
                bcur[j][kq] = bnext[j][kq];

        __syncthreads();   // vmcnt(0)+lgkmcnt(0): drains prefetches issued ~600 cyc ago
    }

    // ---- epilogue: per-row tanh-dot with Vw, reduce over 16 col-lanes, atomicAdd ----
    int bidx = (int)(m0 >> 11);
    const float* qpb = qp + (long)bidx * HH;
    float qv[4], vw[4];
    #pragma unroll
    for (int j = 0; j < 4; ++j) {
        int cg = n0 + wcol + j * 16 + l16;      // C/D col = lane&15
        qv[j] = qpb[cg];
        vw[j] = Vw[cg];
    }
    #pragma unroll
    for (int i = 0; i < 4; ++i) {
        #pragma unroll
        for (int r = 0; r < 4; ++r) {
            float sum = 0.0f;
            #pragma unroll
            for (int j = 0; j < 4; ++j) {
                float xv = acc[i][j][r] + qv[j];
                sum += fast_tanh(xv) * vw[j];
            }
            sum += __shfl_xor(sum, 1);
            sum += __shfl_xor(sum, 2);
            sum += __shfl_xor(sum, 4);
            sum += __shfl_xor(sum, 8);
            if (l16 == 0) {
                // C/D row = quad*4 + reg
                atomicAdd(score + m0 + wrow + i * 16 + quad * 4 + r, sum);
            }
        }
    }
}

// ---------------- softmax over T per batch ----------------
__global__ void softmax_k(const float* __restrict__ sc, float* __restrict__ w) {
    int b = blockIdx.x, tid = threadIdx.x;
    const float* s = sc + (long)b * TT;
    float v[8];
    float4 a0 = *(const float4*)(s + tid * 8);
    float4 a1 = *(const float4*)(s + tid * 8 + 4);
    v[0]=a0.x; v[1]=a0.y; v[2]=a0.z; v[3]=a0.w;
    v[4]=a1.x; v[5]=a1.y; v[6]=a1.z; v[7]=a1.w;
    float mx = v[0];
    #pragma unroll
    for (int i = 1; i < 8; ++i) mx = fmaxf(mx, v[i]);
    #pragma unroll
    for (int m = 1; m < 64; m <<= 1) mx = fmaxf(mx, __shfl_xor(mx, m));
    __shared__ float smx[4], ssum[4];
    int wid = tid >> 6;
    if ((tid & 63) == 0) smx[wid] = mx;
    __syncthreads();
    mx = fmaxf(fmaxf(smx[0], smx[1]), fmaxf(smx[2], smx[3]));
    float sum = 0.0f;
    #pragma unroll
    for (int i = 0; i < 8; ++i) { v[i] = __expf(v[i] - mx); sum += v[i]; }
    #pragma unroll
    for (int m = 1; m < 64; m <<= 1) sum += __shfl_xor(sum, m);
    if ((tid & 63) == 0) ssum[wid] = sum;
    __syncthreads();
    sum = ssum[0] + ssum[1] + ssum[2] + ssum[3];
    float inv = 1.0f / sum;
    float4 o0 = make_float4(v[0]*inv, v[1]*inv, v[2]*inv, v[3]*inv);
    float4 o1 = make_float4(v[4]*inv, v[5]*inv, v[6]*inv, v[7]*inv);
    *(float4*)(w + (long)b * TT + tid * 8)     = o0;
    *(float4*)(w + (long)b * TT + tid * 8 + 4) = o1;
}

// ---------------- context partial (bf16 values): grid (32,16), block 256 ----------------
__global__ void context_k2(const ushort_t* __restrict__ vb, const float* __restrict__ w,
                           float* __restrict__ partial) {
    int b = blockIdx.x, tc = blockIdx.y;
    int tid = threadIdx.x;
    int toff = tid >> 7;            // 0 or 1
    int hi   = tid & 127;
    int h    = hi * 8;
    __shared__ float sw[128];
    __shared__ float red[128][8];
    if (tid < 128) sw[tid] = w[(long)b * TT + tc * 128 + tid];
    __syncthreads();

    const ushort_t* base = vb + ((long)b * TT + tc * 128 + toff) * HH + h;
    float acc[8] = {0.f,0.f,0.f,0.f,0.f,0.f,0.f,0.f};
    #pragma unroll 8
    for (int it = 0; it < 64; ++it) {
        us8 v = *(const us8*)(base + (long)it * 2 * HH);
        float wt = sw[it * 2 + toff];
        #pragma unroll
        for (int e = 0; e < 8; ++e) acc[e] += wt * bf2f(v[e]);
    }
    if (toff == 1) {
        #pragma unroll
        for (int e = 0; e < 8; ++e) red[hi][e] = acc[e];
    }
    __syncthreads();
    if (toff == 0) {
        #pragma unroll
        for (int e = 0; e < 8; ++e) acc[e] += red[hi][e];
        float* p = partial + ((long)tc * 32 + b) * HH + h;
        *(float4*)(p)     = make_float4(acc[0], acc[1], acc[2], acc[3]);
        *(float4*)(p + 4) = make_float4(acc[4], acc[5], acc[6], acc[7]);
    }
}

// ---------------- context reduce: 128 blocks x 256 ----------------
__global__ void context_red_k(const float* __restrict__ partial, float* __restrict__ ctx) {
    int i = blockIdx.x * 256 + threadIdx.x;
    float s = 0.f;
    #pragma unroll
    for (int tc = 0; tc < 16; ++tc) s += partial[(long)tc * 32768 + i];
    ctx[i] = s;
}

extern "C" void kernel_launch(void* const* d_in, const int* in_sizes, int n_in,
                              void* d_out, int out_size, void* d_ws, size_t ws_size,
                              hipStream_t stream) {
    const float* query  = (const float*)d_in[0];
    const float* values = (const float*)d_in[1];
    const float* Wq     = (const float*)d_in[2];
    const float* bq     = (const float*)d_in[3];
    const float* Wv     = (const float*)d_in[4];
    const float* bv     = (const float*)d_in[5];
    const float* Vw     = (const float*)d_in[6];
    // Vb cancels in softmax.

    // workspace layout
    char* ws = (char*)d_ws;
    ushort_t* vb   = (ushort_t*)ws;                                    // 128 MB bf16 values
    ushort_t* wvb  = (ushort_t*)(ws + 134217728);                      // 2 MB bf16 Wv
    float*    qp   = (float*)   (ws + 134217728 + 2097152);            // 128 KB
    float*    scre = (float*)   (ws + 134217728 + 2097152 + 131072);   // 256 KB
    float*    partial = (float*)wvb;  // 2 MB; wvb dead after gemm

    float* ctx  = (float*)d_out;               // [32,1024]
    float* wout = (float*)d_out + BATCH * HH;  // [32,2048,1]

    hipMemsetAsync(scre, 0, (size_t)MTOT * 4, stream);

    // convert values + Wv to bf16
    cvt_bf16_k<<<(BATCH * TT * HH) / 2048, 256, 0, stream>>>(values, vb, (long)BATCH * TT * HH);
    cvt_bf16_k<<<(HH * HH) / 2048, 256, 0, stream>>>(Wv, wvb, (long)HH * HH);

    // q_proj (+bq +bv folded)
    qproj_k<<<HH, 256, 0, stream>>>(query, Wq, bq, bv, qp);

    // fused score GEMM: 512 m-tiles x 8 n-tiles
    score_gemm_k<<<(MTOT / BM) * (HH / BN), 256, 0, stream>>>(vb, wvb, qp, Vw, scre);

    // softmax over T
    softmax_k<<<BATCH, 256, 0, stream>>>(scre, wout);

    // context vector: partials (no atomics) + reduce
    context_k2<<<dim3(BATCH, 16), 256, 0, stream>>>(vb, wout, partial);
    context_red_k<<<(BATCH * HH) / 256, 256, 0, stream>>>(partial, ctx);
}

// Round 5
// 569.268 us; speedup vs baseline: 1.2362x; 1.2362x over previous
//
#include <hip/hip_runtime.h>

// Problem constants
#define BATCH 32
#define TT    2048
#define HH    1024
#define MTOT  (BATCH * TT)   // 65536

typedef unsigned short ushort_t;
typedef short sh8 __attribute__((ext_vector_type(8)));
typedef float f4 __attribute__((ext_vector_type(4)));
typedef unsigned short us8 __attribute__((ext_vector_type(8)));

__device__ __forceinline__ ushort_t f2bf(float f) {
    unsigned u = __float_as_uint(f);
    u = (u + 0x7fffu + ((u >> 16) & 1u)) >> 16;
    return (ushort_t)u;
}
__device__ __forceinline__ float bf2f(ushort_t h) {
    return __uint_as_float(((unsigned)h) << 16);
}
__device__ __forceinline__ float fast_tanh(float x) {
    float e = __expf(2.0f * x);
    return 1.0f - 2.0f * __builtin_amdgcn_rcpf(e + 1.0f);
}

__device__ __forceinline__ void glds16(const void* g, void* l) {
    __builtin_amdgcn_global_load_lds(
        (const __attribute__((address_space(1))) void*)g,
        (__attribute__((address_space(3))) void*)l, 16, 0, 0);
}

// ---------------- fp32 -> bf16 convert (8 elems/thread) ----------------
__global__ void cvt_bf16_k(const float* __restrict__ in, ushort_t* __restrict__ out, long n) {
    long i = ((long)blockIdx.x * blockDim.x + threadIdx.x) * 8;
    if (i + 8 > n) return;
    float4 a = *(const float4*)(in + i);
    float4 b = *(const float4*)(in + i + 4);
    us8 o;
    o[0]=f2bf(a.x); o[1]=f2bf(a.y); o[2]=f2bf(a.z); o[3]=f2bf(a.w);
    o[4]=f2bf(b.x); o[5]=f2bf(b.y); o[6]=f2bf(b.z); o[7]=f2bf(b.w);
    *(us8*)(out + i) = o;
}

// ---------------- q_proj = query @ Wq.T + bq + bv ----------------
__global__ void qproj_k(const float* __restrict__ query, const float* __restrict__ Wq,
                        const float* __restrict__ bq, const float* __restrict__ bv,
                        float* __restrict__ qp) {
    int o = blockIdx.x, tid = threadIdx.x;
    float4 w4 = *(const float4*)(Wq + (long)o * HH + tid * 4);
    __shared__ float sm[BATCH][4];
    int wid = tid >> 6, lane = tid & 63;
    for (int b = 0; b < BATCH; ++b) {
        float4 q4 = *(const float4*)(query + (long)b * HH + tid * 4);
        float p = q4.x*w4.x + q4.y*w4.y + q4.z*w4.z + q4.w*w4.w;
        #pragma unroll
        for (int m = 1; m < 64; m <<= 1) p += __shfl_xor(p, m);
        if (lane == 0) sm[b][wid] = p;
    }
    __syncthreads();
    if (tid < BATCH) {
        float s = sm[tid][0] + sm[tid][1] + sm[tid][2] + sm[tid][3] + bq[o] + bv[o];
        qp[(long)tid * HH + o] = s;
    }
}

// ---------------- fused score GEMM (R2 structure: A+B via glds, single-buffer) ----------------
// Epilogue writes plain partial slices spart[nt*2 + colhalf][m] (no atomics, no memset).
#define BM 128
#define BN 128
#define BK 64

__global__ __launch_bounds__(256, 2) void score_gemm_k(
    const ushort_t* __restrict__ A, const ushort_t* __restrict__ Bw,
    const float* __restrict__ qp, const float* __restrict__ Vw,
    float* __restrict__ spart)
{
    __shared__ ushort_t As[BM * BK];   // 16 KB
    __shared__ ushort_t Bs[BN * BK];   // 16 KB
    int tid = threadIdx.x;

    // XCD-aware swizzle: the 8 n-tiles of one m-tile share bx%8 -> same XCD (A reuse in L2)
    int bx = blockIdx.x;
    int x  = bx & 7;
    int s  = bx >> 3;
    int nt = s & 7;
    int mt = ((s >> 3) << 3) | x;          // 0..511
    const long m0 = (long)mt * BM;
    const int  n0 = nt * BN;

    int wid  = tid >> 6, lane = tid & 63;
    int quad = lane >> 4, l16 = lane & 15;
    int wrow = (wid >> 1) * 64, wcol = (wid & 1) * 64;

    f4 acc[4][4] = {};

    // staging: thread -> (row = tid/8, 16B seg = tid%8), seg XOR-swizzled by row&7
    int srow = tid >> 3;
    int sseg = tid & 7;
    int xseg = sseg ^ (srow & 7);
    const ushort_t* Ag = A  + (m0 + srow) * (long)HH + xseg * 8;
    const ushort_t* Bg = Bw + (long)(n0 + srow) * HH + xseg * 8;
    char* AsB = (char*)As;
    char* BsB = (char*)Bs;
    const int woff = wid * 1024;   // wave-uniform; HW adds lane*16

    for (int kt = 0; kt < HH / BK; ++kt) {
        const int kb = kt * BK;
        #pragma unroll
        for (int c = 0; c < 4; ++c) {
            glds16(Ag + (long)c * 32 * HH + kb, AsB + c * 4096 + woff);
            glds16(Bg + (long)c * 32 * HH + kb, BsB + c * 4096 + woff);
        }
        __syncthreads();

        sh8 af[4][2], bf[4][2];
        #pragma unroll
        for (int i = 0; i < 4; ++i) {
            int r = wrow + i * 16 + l16;
            #pragma unroll
            for (int kq = 0; kq < 2; ++kq) {
                int sg = (kq * 4 + quad) ^ (r & 7);
                af[i][kq] = *(const sh8*)(AsB + r * 128 + sg * 16);
            }
        }
        #pragma unroll
        for (int j = 0; j < 4; ++j) {
            int r = wcol + j * 16 + l16;
            #pragma unroll
            for (int kq = 0; kq < 2; ++kq) {
                int sg = (kq * 4 + quad) ^ (r & 7);
                bf[j][kq] = *(const sh8*)(BsB + r * 128 + sg * 16);
            }
        }
        #pragma unroll
        for (int kq = 0; kq < 2; ++kq)
            #pragma unroll
            for (int i = 0; i < 4; ++i)
                #pragma unroll
                for (int j = 0; j < 4; ++j)
                    acc[i][j] = __builtin_amdgcn_mfma_f32_16x16x32_bf16(
                        af[i][kq], bf[j][kq], acc[i][j], 0, 0, 0);
        __syncthreads();
    }

    // ---- epilogue: per-row tanh-dot with Vw, reduce over 16 col-lanes, plain store ----
    int bidx = (int)(m0 >> 11);
    const float* qpb = qp + (long)bidx * HH;
    float qv[4], vw[4];
    #pragma unroll
    for (int j = 0; j < 4; ++j) {
        int cg = n0 + wcol + j * 16 + l16;      // C/D col = lane&15
        qv[j] = qpb[cg];
        vw[j] = Vw[cg];
    }
    // slice = nt*2 + (wid&1): waves sharing the same rows (same wrow, different wcol)
    // write disjoint slices; softmax sums all 16.
    float* sp = spart + (long)(nt * 2 + (wid & 1)) * MTOT + m0;
    #pragma unroll
    for (int i = 0; i < 4; ++i) {
        #pragma unroll
        for (int r = 0; r < 4; ++r) {
            float sum = 0.0f;
            #pragma unroll
            for (int j = 0; j < 4; ++j) {
                float xv = acc[i][j][r] + qv[j];
                sum += fast_tanh(xv) * vw[j];
            }
            sum += __shfl_xor(sum, 1);
            sum += __shfl_xor(sum, 2);
            sum += __shfl_xor(sum, 4);
            sum += __shfl_xor(sum, 8);
            if (l16 == 0) {
                // C/D row = quad*4 + reg
                sp[wrow + i * 16 + quad * 4 + r] = sum;
            }
        }
    }
}

// ---------------- softmax over T per batch (sums 16 partial slices) ----------------
__global__ void softmax_k(const float* __restrict__ spart, float* __restrict__ w) {
    int b = blockIdx.x, tid = threadIdx.x;
    const long base = (long)b * TT + tid * 8;
    float v[8] = {0.f,0.f,0.f,0.f,0.f,0.f,0.f,0.f};
    #pragma unroll
    for (int k = 0; k < 16; ++k) {
        const float* p = spart + (long)k * MTOT + base;
        float4 a0 = *(const float4*)(p);
        float4 a1 = *(const float4*)(p + 4);
        v[0]+=a0.x; v[1]+=a0.y; v[2]+=a0.z; v[3]+=a0.w;
        v[4]+=a1.x; v[5]+=a1.y; v[6]+=a1.z; v[7]+=a1.w;
    }
    float mx = v[0];
    #pragma unroll
    for (int i = 1; i < 8; ++i) mx = fmaxf(mx, v[i]);
    #pragma unroll
    for (int m = 1; m < 64; m <<= 1) mx = fmaxf(mx, __shfl_xor(mx, m));
    __shared__ float smx[4], ssum[4];
    int wid = tid >> 6;
    if ((tid & 63) == 0) smx[wid] = mx;
    __syncthreads();
    mx = fmaxf(fmaxf(smx[0], smx[1]), fmaxf(smx[2], smx[3]));
    float sum = 0.0f;
    #pragma unroll
    for (int i = 0; i < 8; ++i) { v[i] = __expf(v[i] - mx); sum += v[i]; }
    #pragma unroll
    for (int m = 1; m < 64; m <<= 1) sum += __shfl_xor(sum, m);
    if ((tid & 63) == 0) ssum[wid] = sum;
    __syncthreads();
    sum = ssum[0] + ssum[1] + ssum[2] + ssum[3];
    float inv = 1.0f / sum;
    float4 o0 = make_float4(v[0]*inv, v[1]*inv, v[2]*inv, v[3]*inv);
    float4 o1 = make_float4(v[4]*inv, v[5]*inv, v[6]*inv, v[7]*inv);
    *(float4*)(w + (long)b * TT + tid * 8)     = o0;
    *(float4*)(w + (long)b * TT + tid * 8 + 4) = o1;
}

// ---------------- context partial (bf16 values): grid (32,32), block 256 ----------------
__global__ void context_k2(const ushort_t* __restrict__ vb, const float* __restrict__ w,
                           float* __restrict__ cpart) {
    int b = blockIdx.x, tc = blockIdx.y;   // tc: chunk of 64 t's
    int tid = threadIdx.x;
    int toff = tid >> 7;            // 0 or 1
    int hi   = tid & 127;
    int h    = hi * 8;
    __shared__ float sw[64];
    __shared__ float red[128][8];
    if (tid < 64) sw[tid] = w[(long)b * TT + tc * 64 + tid];
    __syncthreads();

    const ushort_t* base = vb + ((long)b * TT + tc * 64 + toff) * HH + h;
    float acc[8] = {0.f,0.f,0.f,0.f,0.f,0.f,0.f,0.f};
    #pragma unroll 8
    for (int it = 0; it < 32; ++it) {
        us8 v = *(const us8*)(base + (long)it * 2 * HH);
        float wt = sw[it * 2 + toff];
        #pragma unroll
        for (int e = 0; e < 8; ++e) acc[e] += wt * bf2f(v[e]);
    }
    if (toff == 1) {
        #pragma unroll
        for (int e = 0; e < 8; ++e) red[hi][e] = acc[e];
    }
    __syncthreads();
    if (toff == 0) {
        #pragma unroll
        for (int e = 0; e < 8; ++e) acc[e] += red[hi][e];
        float* p = cpart + ((long)tc * 32 + b) * HH + h;
        *(float4*)(p)     = make_float4(acc[0], acc[1], acc[2], acc[3]);
        *(float4*)(p + 4) = make_float4(acc[4], acc[5], acc[6], acc[7]);
    }
}

// ---------------- context reduce: 128 blocks x 256 ----------------
__global__ void context_red_k(const float* __restrict__ cpart, float* __restrict__ ctx) {
    int i = blockIdx.x * 256 + threadIdx.x;
    float s = 0.f;
    #pragma unroll
    for (int tc = 0; tc < 32; ++tc) s += cpart[(long)tc * 32768 + i];
    ctx[i] = s;
}

extern "C" void kernel_launch(void* const* d_in, const int* in_sizes, int n_in,
                              void* d_out, int out_size, void* d_ws, size_t ws_size,
                              hipStream_t stream) {
    const float* query  = (const float*)d_in[0];
    const float* values = (const float*)d_in[1];
    const float* Wq     = (const float*)d_in[2];
    const float* bq     = (const float*)d_in[3];
    const float* Wv     = (const float*)d_in[4];
    const float* bv     = (const float*)d_in[5];
    const float* Vw     = (const float*)d_in[6];
    // Vb cancels in softmax.

    // workspace layout
    char* ws = (char*)d_ws;
    ushort_t* vb    = (ushort_t*)ws;                         // 128 MB bf16 values
    ushort_t* wvb   = (ushort_t*)(ws + 134217728);           // 2 MB bf16 Wv
    float*    qp    = (float*)   (ws + 136314880);           // 128 KB
    float*    spart = (float*)   (ws + 136445952);           // 16*65536*4 = 4 MB
    float*    cpart = (float*)   (ws + 140640256);           // 32*32768*4 = 4 MB

    float* ctx  = (float*)d_out;               // [32,1024]
    float* wout = (float*)d_out + BATCH * HH;  // [32,2048,1]

    // convert values + Wv to bf16
    cvt_bf16_k<<<(BATCH * TT * HH) / 2048, 256, 0, stream>>>(values, vb, (long)BATCH * TT * HH);
    cvt_bf16_k<<<(HH * HH) / 2048, 256, 0, stream>>>(Wv, wvb, (long)HH * HH);

    // q_proj (+bq +bv folded)
    qproj_k<<<HH, 256, 0, stream>>>(query, Wq, bq, bv, qp);

    // fused score GEMM: 512 m-tiles x 8 n-tiles -> 16 partial slices
    score_gemm_k<<<(MTOT / BM) * (HH / BN), 256, 0, stream>>>(vb, wvb, qp, Vw, spart);

    // softmax over T (sums 16 slices)
    softmax_k<<<BATCH, 256, 0, stream>>>(spart, wout);

    // context vector: partials (no atomics) + reduce
    context_k2<<<dim3(BATCH, 32), 256, 0, stream>>>(vb, wout, cpart);
    context_red_k<<<(BATCH * HH) / 256, 256, 0, stream>>>(cpart, ctx);
}